// Round 7
// baseline (206.917 us; speedup 1.0000x reference)
//
#include <hip/hip_runtime.h>

// pol[g] = sum_{i in g} (q_i - mean(q)) * r_i = (sum_g q r) - mean * (sum_g r)
// pol_main: 2048 blocks x 256 thr; each WAVE owns 1024 consecutive nodes and
//   loads its pos region with fully DENSE float4 loads (lane i -> Wp+i+64k).
//   q multipliers come from q4[m/3] (dense, L1-served). Phase algebra
//   (ph = m%3) maps float4 components to xyz without any transpose; per-phase
//   float4 accumulators recombined at the end. Segment split via integer
//   compare on component float index (4m+c < 3*split). Pure-segment waves
//   take a mask-free fast path. Records/finalize: proven round-4 structure.

#define N_NODES         8388608
#define NUM_GRAPHS      1024
#define BLK             256
#define NODES_PER_BLOCK 4096
#define NBLOCKS         (N_NODES / NODES_PER_BLOCK)     // 2048
#define ITER            4
#define NSLOT           4

// ws layout (float offsets)
#define IBASE_OFF       16                               // int ibase[NBLOCKS]
#define SPLIT_OFF       2064                             // int4 split[NBLOCKS]
#define REC_OFF         10256                            // rec[NBLOCKS][32]
#define REC_STRIDE      32
#define EXTRA_OFF       (REC_OFF + NBLOCKS * REC_STRIDE) // 75792
#define WS_FLOATS       (EXTRA_OFF + NUM_GRAPHS * 6)     // 81936 floats

__device__ __forceinline__ float4 f4z() { return make_float4(0.f, 0.f, 0.f, 0.f); }
__device__ __forceinline__ float4 f4add(float4 a, float4 b) {
    return make_float4(a.x + b.x, a.y + b.y, a.z + b.z, a.w + b.w);
}
__device__ __forceinline__ float4 f4mul(float4 a, float4 b) {
    return make_float4(a.x * b.x, a.y * b.y, a.z * b.z, a.w * b.w);
}
__device__ __forceinline__ float4 f4sel(bool c, float4 a) {
    return make_float4(c ? a.x : 0.f, c ? a.y : 0.f, c ? a.z : 0.f, c ? a.w : 0.f);
}

__global__ __launch_bounds__(BLK) void split_kernel(const int* __restrict__ batch,
                                                    float* __restrict__ ws) {
    int b = blockIdx.x * BLK + threadIdx.x;
    if (b >= NBLOCKS) return;
    float* extra = ws + EXTRA_OFF;
    extra[b * 3 + 0] = 0.f; extra[b * 3 + 1] = 0.f; extra[b * 3 + 2] = 0.f;

    const int s = b * NODES_PER_BLOCK;
    const int e = s + NODES_PER_BLOCK;
    int i0 = batch[s];
    int i1 = batch[e - 1];
    int split = e;
    if (i1 != i0) {
        int lo = s + 1, hi = e - 1;
        while (lo < hi) {
            int mid = (lo + hi) >> 1;
            if (batch[mid] > i0) hi = mid; else lo = mid + 1;
        }
        split = lo;
    }
    ((int4*)(ws + SPLIT_OFF))[b] = make_int4(i0, i1, split, 0);
    ((int*)(ws + IBASE_OFF))[b] = i0;
}

__device__ __forceinline__ void flush_seg(int id, int base,
                                          float qx, float qy, float qz,
                                          float rx, float ry, float rz,
                                          float* sslot, float* extra) {
    int s = id - base;
    if (s >= 0 && s < NSLOT) {
        atomicAdd(&sslot[s * 6 + 0], qx); atomicAdd(&sslot[s * 6 + 1], qy);
        atomicAdd(&sslot[s * 6 + 2], qz); atomicAdd(&sslot[s * 6 + 3], rx);
        atomicAdd(&sslot[s * 6 + 4], ry); atomicAdd(&sslot[s * 6 + 5], rz);
    } else {
        atomicAdd(&extra[id * 6 + 0], qx); atomicAdd(&extra[id * 6 + 1], qy);
        atomicAdd(&extra[id * 6 + 2], qz); atomicAdd(&extra[id * 6 + 3], rx);
        atomicAdd(&extra[id * 6 + 4], ry); atomicAdd(&extra[id * 6 + 5], rz);
    }
}

#define PHACC(a0, a1, a2, u) \
    { a0 = f4add(a0, f4sel(ph == 0, u)); \
      a1 = f4add(a1, f4sel(ph == 1, u)); \
      a2 = f4add(a2, f4sel(ph == 2, u)); }

__global__ __launch_bounds__(BLK) void pol_main(const float4* __restrict__ p4,
                                                const float4* __restrict__ q4,
                                                const int*    __restrict__ batch,
                                                float* __restrict__ ws) {
    __shared__ float sslot[NSLOT * 6];
    __shared__ float sqsum;

    const int t = threadIdx.x;
    const int b = blockIdx.x;
    float* extra = ws + EXTRA_OFF;

    const int4 si = ((const int4*)(ws + SPLIT_OFF))[b];
    const int i0 = si.x, i1 = si.y, split = si.z;
    const bool general = (i1 > i0 + 1);   // >=3 graphs in one block: impossible here

    if (t < NSLOT * 6) sslot[t] = 0.f;
    if (t == 0) sqsum = 0.f;
    __syncthreads();

    float qsum = 0.f;

    if (!general) {
        const int lane   = t & 63;
        const int region = b * 4 + (t >> 6);       // wave-region: 1024 nodes
        const int n0     = region * 1024;
        const int Wp     = region * 768;           // pos float4 base (768 per region)
        const bool allB  = (split <= n0);
        const bool mixed = (split > n0) && (split < n0 + 1024);
        const int fsplit = split * 3;              // component-float split index

        float4 V0[4], Q0[4], V1[4], Q1[4];
        auto ldg = [&](float4* Vv, float4* Qv, int g) {
            #pragma unroll
            for (int k2 = 0; k2 < 4; ++k2) {
                int m = Wp + lane + 64 * (g * 4 + k2);
                Vv[k2] = p4[m];
                Qv[k2] = q4[(unsigned)m / 3u];
            }
        };

        float4 qrA0 = f4z(), qrA1 = f4z(), qrA2 = f4z();
        float4 rA0  = f4z(), rA1  = f4z(), rA2  = f4z();
        float4 qrB0 = f4z(), qrB1 = f4z(), qrB2 = f4z();
        float4 rB0  = f4z(), rB1  = f4z(), rB2  = f4z();

        auto comp_pure = [&](const float4* Vv, const float4* Qv, int g) {
            #pragma unroll
            for (int k2 = 0; k2 < 4; ++k2) {
                int m = Wp + lane + 64 * (g * 4 + k2);
                int s3 = (int)((unsigned)m / 3u);
                int ph = m - 3 * s3;
                float4 v = Vv[k2], qq = Qv[k2];
                float4 qv;
                qv.x = ph == 0 ? qq.x : (ph == 1 ? qq.y : qq.z);
                qv.y = ph == 0 ? qq.x : (ph == 1 ? qq.y : qq.w);
                qv.z = ph == 0 ? qq.x : (ph == 1 ? qq.z : qq.w);
                qv.w = ph == 0 ? qq.y : (ph == 1 ? qq.z : qq.w);
                qsum += (ph == 0) ? (qq.x + qq.y) + (qq.z + qq.w) : 0.f;
                float4 u = f4mul(v, qv);
                PHACC(qrA0, qrA1, qrA2, u);
                PHACC(rA0, rA1, rA2, v);
            }
        };
        auto comp_mixed = [&](const float4* Vv, const float4* Qv, int g) {
            #pragma unroll
            for (int k2 = 0; k2 < 4; ++k2) {
                int m = Wp + lane + 64 * (g * 4 + k2);
                int s3 = (int)((unsigned)m / 3u);
                int ph = m - 3 * s3;
                float4 v = Vv[k2], qq = Qv[k2];
                float4 qv;
                qv.x = ph == 0 ? qq.x : (ph == 1 ? qq.y : qq.z);
                qv.y = ph == 0 ? qq.x : (ph == 1 ? qq.y : qq.w);
                qv.z = ph == 0 ? qq.x : (ph == 1 ? qq.z : qq.w);
                qv.w = ph == 0 ? qq.y : (ph == 1 ? qq.z : qq.w);
                qsum += (ph == 0) ? (qq.x + qq.y) + (qq.z + qq.w) : 0.f;
                int f0 = 4 * m;
                float4 vA;  // component node < split ?
                vA.x = (f0 + 0 < fsplit) ? v.x : 0.f;
                vA.y = (f0 + 1 < fsplit) ? v.y : 0.f;
                vA.z = (f0 + 2 < fsplit) ? v.z : 0.f;
                vA.w = (f0 + 3 < fsplit) ? v.w : 0.f;
                float4 vB = make_float4(v.x - vA.x, v.y - vA.y, v.z - vA.z, v.w - vA.w);
                float4 uA = f4mul(vA, qv);
                float4 uB = f4mul(vB, qv);
                PHACC(qrA0, qrA1, qrA2, uA);
                PHACC(rA0, rA1, rA2, vA);
                PHACC(qrB0, qrB1, qrB2, uB);
                PHACC(rB0, rB1, rB2, vB);
            }
        };

        ldg(V0, Q0, 0);
        ldg(V1, Q1, 1);
        if (!mixed) {
            comp_pure(V0, Q0, 0);
            ldg(V0, Q0, 2);
            comp_pure(V1, Q1, 1);
            comp_pure(V0, Q0, 2);
        } else {
            comp_mixed(V0, Q0, 0);
            ldg(V0, Q0, 2);
            comp_mixed(V1, Q1, 1);
            comp_mixed(V0, Q0, 2);
        }

        // recombine phase accumulators -> xyz (coord map: ph0=(x,y,z,x),
        // ph1=(y,z,x,y), ph2=(z,x,y,z))
        float AX = qrA0.x + qrA0.w + qrA1.z + qrA2.y;
        float AY = qrA0.y + qrA1.x + qrA1.w + qrA2.z;
        float AZ = qrA0.z + qrA1.y + qrA2.x + qrA2.w;
        float ARX = rA0.x + rA0.w + rA1.z + rA2.y;
        float ARY = rA0.y + rA1.x + rA1.w + rA2.z;
        float ARZ = rA0.z + rA1.y + rA2.x + rA2.w;
        #pragma unroll
        for (int off = 32; off > 0; off >>= 1) {
            AX += __shfl_down(AX, off, 64);  AY += __shfl_down(AY, off, 64);
            AZ += __shfl_down(AZ, off, 64);  ARX += __shfl_down(ARX, off, 64);
            ARY += __shfl_down(ARY, off, 64); ARZ += __shfl_down(ARZ, off, 64);
        }
        if (lane == 0) {
            int gid = (!mixed && allB) ? i1 : i0;   // pure region's graph, or mixed A-part
            flush_seg(gid, i0, AX, AY, AZ, ARX, ARY, ARZ, sslot, extra);
        }
        if (mixed) {
            float BX = qrB0.x + qrB0.w + qrB1.z + qrB2.y;
            float BY = qrB0.y + qrB1.x + qrB1.w + qrB2.z;
            float BZ = qrB0.z + qrB1.y + qrB2.x + qrB2.w;
            float BRX = rB0.x + rB0.w + rB1.z + rB2.y;
            float BRY = rB0.y + rB1.x + rB1.w + rB2.z;
            float BRZ = rB0.z + rB1.y + rB2.x + rB2.w;
            #pragma unroll
            for (int off = 32; off > 0; off >>= 1) {
                BX += __shfl_down(BX, off, 64);  BY += __shfl_down(BY, off, 64);
                BZ += __shfl_down(BZ, off, 64);  BRX += __shfl_down(BRX, off, 64);
                BRY += __shfl_down(BRY, off, 64); BRZ += __shfl_down(BRZ, off, 64);
            }
            if (lane == 0)
                flush_seg(i1, i0, BX, BY, BZ, BRX, BRY, BRZ, sslot, extra);
        }
    } else {
        // >=3 graphs in block (never for this input): per-node atomics, correct
        const int blk_v4 = b * (NODES_PER_BLOCK / 4);
        for (int j = 0; j < ITER; ++j) {
            int vi = blk_v4 + j * BLK + t;
            float4 qv = q4[vi];
            float4 p0 = p4[3 * vi + 0];
            float4 p1 = p4[3 * vi + 1];
            float4 p2 = p4[3 * vi + 2];
            float qs[4] = {qv.x, qv.y, qv.z, qv.w};
            float px[4] = {p0.x, p0.w, p1.z, p2.y};
            float py[4] = {p0.y, p1.x, p1.w, p2.z};
            float pz[4] = {p0.z, p1.y, p2.x, p2.w};
            for (int k = 0; k < 4; ++k) {
                int id = batch[vi * 4 + k];
                float qj = qs[k];
                qsum += qj;
                atomicAdd(&extra[id * 6 + 0], qj * px[k]);
                atomicAdd(&extra[id * 6 + 1], qj * py[k]);
                atomicAdd(&extra[id * 6 + 2], qj * pz[k]);
                atomicAdd(&extra[id * 6 + 3], px[k]);
                atomicAdd(&extra[id * 6 + 4], py[k]);
                atomicAdd(&extra[id * 6 + 5], pz[k]);
            }
        }
    }

    // block qsum
    #pragma unroll
    for (int off = 32; off > 0; off >>= 1) qsum += __shfl_down(qsum, off, 64);
    if ((t & 63) == 0) atomicAdd(&sqsum, qsum);
    __syncthreads();

    float* rec = ws + REC_OFF + (size_t)b * REC_STRIDE;
    if (t == 0) rec[0] = sqsum;
    if (t < NSLOT * 6) rec[8 + t] = sslot[t];
}

// Single block, 1024 threads: mean from 2048 block qsums, then per-graph gather
// via binary search over sorted block base ids (rounds 3-6 proven logic).
__global__ __launch_bounds__(1024) void finalize_kernel(const float* __restrict__ ws,
                                                        float* __restrict__ out) {
    __shared__ float sm[16];
    __shared__ float smean;
    const int t = threadIdx.x;

    float s = ws[REC_OFF + (size_t)t * REC_STRIDE]
            + ws[REC_OFF + (size_t)(t + 1024) * REC_STRIDE];
    #pragma unroll
    for (int off = 32; off > 0; off >>= 1) s += __shfl_down(s, off, 64);
    if ((t & 63) == 0) sm[t >> 6] = s;
    __syncthreads();
    if (t == 0) {
        float tot = 0.f;
        #pragma unroll
        for (int i = 0; i < 16; ++i) tot += sm[i];
        smean = tot * (1.0f / (float)N_NODES);
    }
    __syncthreads();
    const float mean = smean;

    const int g = t;
    const int* ibase = (const int*)(ws + IBASE_OFF);
    const float* extra = ws + EXTRA_OFF;

    float qx = extra[g * 6 + 0], qy = extra[g * 6 + 1], qz = extra[g * 6 + 2];
    float rx = extra[g * 6 + 3], ry = extra[g * 6 + 4], rz = extra[g * 6 + 5];

    int lo = 0, hi = NBLOCKS - 1, B = -1;
    while (lo <= hi) {
        int mid = (lo + hi) >> 1;
        if (ibase[mid] <= g) { B = mid; lo = mid + 1; } else hi = mid - 1;
    }
    for (int b = B; b >= 0; --b) {
        int sl = g - ibase[b];
        if (sl >= NSLOT) break;
        const float* p = ws + REC_OFF + (size_t)b * REC_STRIDE + 8 + sl * 6;
        qx += p[0]; qy += p[1]; qz += p[2];
        rx += p[3]; ry += p[4]; rz += p[5];
    }
    out[g * 3 + 0] = fmaf(-mean, rx, qx);
    out[g * 3 + 1] = fmaf(-mean, ry, qy);
    out[g * 3 + 2] = fmaf(-mean, rz, qz);
}

// ---------------- fallback path (round-1 code, known correct) ----------------

__global__ void sum_q_kernel(const float* __restrict__ q, float* __restrict__ ws, int n4) {
    int tid = blockIdx.x * blockDim.x + threadIdx.x;
    int stride = gridDim.x * blockDim.x;
    const float4* q4 = (const float4*)q;
    float s = 0.f;
    for (int i = tid; i < n4; i += stride) {
        float4 v = q4[i];
        s += (v.x + v.y) + (v.z + v.w);
    }
    for (int off = 32; off > 0; off >>= 1) s += __shfl_down(s, off, 64);
    __shared__ float smem[4];
    int lane = threadIdx.x & 63, wave = threadIdx.x >> 6;
    if (lane == 0) smem[wave] = s;
    __syncthreads();
    if (threadIdx.x == 0) atomicAdd(ws, (smem[0] + smem[1]) + (smem[2] + smem[3]));
}

__global__ void pol_atomic_kernel(const float* __restrict__ pos,
                                  const float* __restrict__ q,
                                  const int*   __restrict__ batch,
                                  const float* __restrict__ ws,
                                  float* __restrict__ out, int n) {
    const float mean = ws[0] * (1.0f / (float)N_NODES);
    int tid = blockIdx.x * blockDim.x + threadIdx.x;
    int stride = gridDim.x * blockDim.x;
    int n4 = n >> 2;
    const float4* q4 = (const float4*)q;
    const int4*   b4 = (const int4*)batch;
    const float4* p4 = (const float4*)pos;

    for (int i = tid; i < n4; i += stride) {
        float4 qv = q4[i];
        int4   bv = b4[i];
        float4 p0 = p4[3 * i + 0];
        float4 p1 = p4[3 * i + 1];
        float4 p2 = p4[3 * i + 2];
        float qs[4] = {qv.x - mean, qv.y - mean, qv.z - mean, qv.w - mean};
        int  ids[4] = {bv.x, bv.y, bv.z, bv.w};
        float px[4] = {p0.x, p0.w, p1.z, p2.y};
        float py[4] = {p0.y, p1.x, p1.w, p2.z};
        float pz[4] = {p0.z, p1.y, p2.x, p2.w};
        int cur = ids[0];
        float sx = 0.f, sy = 0.f, sz = 0.f;
        #pragma unroll
        for (int j = 0; j < 4; ++j) {
            if (ids[j] != cur) {
                atomicAdd(&out[cur * 3 + 0], sx);
                atomicAdd(&out[cur * 3 + 1], sy);
                atomicAdd(&out[cur * 3 + 2], sz);
                sx = sy = sz = 0.f;
                cur = ids[j];
            }
            sx = fmaf(qs[j], px[j], sx);
            sy = fmaf(qs[j], py[j], sy);
            sz = fmaf(qs[j], pz[j], sz);
        }
        int first = __shfl(cur, 0, 64);
        bool uniform = __all(cur == first);
        if (uniform) {
            for (int off = 32; off > 0; off >>= 1) {
                sx += __shfl_down(sx, off, 64);
                sy += __shfl_down(sy, off, 64);
                sz += __shfl_down(sz, off, 64);
            }
            if ((threadIdx.x & 63) == 0) {
                atomicAdd(&out[cur * 3 + 0], sx);
                atomicAdd(&out[cur * 3 + 1], sy);
                atomicAdd(&out[cur * 3 + 2], sz);
            }
        } else {
            atomicAdd(&out[cur * 3 + 0], sx);
            atomicAdd(&out[cur * 3 + 1], sy);
            atomicAdd(&out[cur * 3 + 2], sz);
        }
    }
}

extern "C" void kernel_launch(void* const* d_in, const int* in_sizes, int n_in,
                              void* d_out, int out_size, void* d_ws, size_t ws_size,
                              hipStream_t stream) {
    const float* pos   = (const float*)d_in[0];
    const float* q     = (const float*)d_in[1];
    const int*   batch = (const int*)d_in[2];
    float* out = (float*)d_out;
    float* ws  = (float*)d_ws;
    int n = in_sizes[1];

    if (ws_size >= (size_t)WS_FLOATS * sizeof(float)) {
        split_kernel<<<NBLOCKS / BLK, BLK, 0, stream>>>(batch, ws);   // 8 blocks
        pol_main<<<NBLOCKS, BLK, 0, stream>>>((const float4*)pos, (const float4*)q,
                                              batch, ws);
        finalize_kernel<<<1, 1024, 0, stream>>>(ws, out);
    } else {
        hipMemsetAsync(d_out, 0, (size_t)out_size * sizeof(float), stream);
        hipMemsetAsync(d_ws, 0, sizeof(float), stream);
        sum_q_kernel<<<4096, BLK, 0, stream>>>(q, ws, n >> 2);
        pol_atomic_kernel<<<8192, BLK, 0, stream>>>(pos, q, batch, ws, out, n);
    }
}